// Round 15
// baseline (147.006 us; speedup 1.0000x reference)
//
#include <hip/hip_runtime.h>

// Navier-Stokes physics-informed loss (f32 in, scalar f32 out).
// x,y: (64,3,512,512). Interior: b in [1,62], i,j in [1,510].
// r0 = |dudx + dvdy| ; r1 = |dudt + u*dudx + v*dudy + dpdx - MU*lap u| ;
// r2 = |dvdt + u*dvdx + v*dvdy + dpdy - MU*lap v| ; dudt=(u[b+1]-u[b-1])*32
//
// R14 broke the 142us plateau (124us wall): LDS center-sharing + prefetch
// + raw-barrier pipeline cut requested bytes to ~0.6GB (below the 10-11TB/s
// service law). Remaining stall: only 2 blocks/CU (48KiB LDS) -> the 2
// barriers/iter serialize with almost no co-resident cover.
// R15: same pipeline, quarter-size blocks. 256 thr = 4 rows x 64 f4-cols
// (half row), LDS 24KiB -> 4-5 blocks/CU; barrier drains overlap across
// blocks. j-half boundary lanes (jt 0/63) get scalars from prefetched
// carried regs. Grid 1024 = 4 b-chunks x 2 j-halves x 128 bands; the 8
// (z,jh) groups map 1:1 onto 8 XCDs.

constexpr int Wd   = 512;
constexpr int CSTR = 512 * 512;
constexpr int BSTR = 3 * 512 * 512;

__device__ __forceinline__ float4 ld4(const float* p) {
    return *reinterpret_cast<const float4*>(p);
}
__device__ __forceinline__ float4 scale4(float4 a, float s) {
    return make_float4(a.x * s, a.y * s, a.z * s, a.w * s);
}

// Residuals for one tensor at the current plane.
// L: [field u,v,p][row 0..3][256 floats] (this tensor's slab, scaled u,v; raw p)
// eu,ev (scaled) / ep (raw): band-edge row for io 0/3.
// mu,cu,nus / mv,cv,nvs: centers at b-1,b,b+1 (scaled). cp: raw p center.
// uL,vL,pL / uR,vR,pR: carried boundary scalars (col j0-1 / j0+4) for lanes 0/63.
__device__ __forceinline__ void plane_resid(
    const float (&L)[3][4][256],
    int io, int jt, int jl,
    float4 eu, float4 ev, float4 ep,
    float4 mu, float4 cu, float4 nus,
    float4 mv, float4 cv, float4 nvs,
    float4 cp,
    float uL, float vL, float pL,
    float uR, float vR, float pR,
    float sdx,
    float r0[4], float r1[4], float r2[4])
{
    float4 uxm, vxm, pxm, uxp, vxp, pxp;
    if (io == 0) { uxm = eu; vxm = ev; pxm = ep; }
    else {
        uxm = ld4(&L[0][io - 1][jl]);
        vxm = ld4(&L[1][io - 1][jl]);
        pxm = ld4(&L[2][io - 1][jl]);
    }
    if (io == 3) { uxp = eu; vxp = ev; pxp = ep; }
    else {
        uxp = ld4(&L[0][io + 1][jl]);
        vxp = ld4(&L[1][io + 1][jl]);
        pxp = ld4(&L[2][io + 1][jl]);
    }

    // j-neighbors: shfl within the wave (one wave == one row of 64 f4-cols);
    // boundary lanes use prefetched carried scalars.
    float u_l = __shfl_up(cu.w, 1);
    float v_l = __shfl_up(cv.w, 1);
    float p_l = __shfl_up(cp.w, 1);
    float u_r = __shfl_down(cu.x, 1);
    float v_r = __shfl_down(cv.x, 1);
    float p_r = __shfl_down(cp.x, 1);
    if (jt == 0)  { u_l = uL; v_l = vL; p_l = pL; }
    if (jt == 63) { u_r = uR; v_r = vR; p_r = pR; }

    const float ucA[4] = {cu.x, cu.y, cu.z, cu.w};
    const float vcA[4] = {cv.x, cv.y, cv.z, cv.w};
    const float umA[4] = {mu.x, mu.y, mu.z, mu.w};
    const float vmA[4] = {mv.x, mv.y, mv.z, mv.w};
    const float unA[4] = {nus.x, nus.y, nus.z, nus.w};
    const float vnA[4] = {nvs.x, nvs.y, nvs.z, nvs.w};
    const float ul[4]  = {u_l, cu.x, cu.y, cu.z};
    const float ur[4]  = {cu.y, cu.z, cu.w, u_r};
    const float vl[4]  = {v_l, cv.x, cv.y, cv.z};
    const float vr[4]  = {cv.y, cv.z, cv.w, v_r};
    const float pl[4]  = {p_l, cp.x, cp.y, cp.z};
    const float pr[4]  = {cp.y, cp.z, cp.w, p_r};
    const float uxpA[4] = {uxp.x, uxp.y, uxp.z, uxp.w};
    const float uxmA[4] = {uxm.x, uxm.y, uxm.z, uxm.w};
    const float vxpA[4] = {vxp.x, vxp.y, vxp.z, vxp.w};
    const float vxmA[4] = {vxm.x, vxm.y, vxm.z, vxm.w};
    const float pxpA[4] = {pxp.x, pxp.y, pxp.z, pxp.w};
    const float pxmA[4] = {pxm.x, pxm.y, pxm.z, pxm.w};

    #pragma unroll
    for (int k = 0; k < 4; ++k) {
        const float dudx = (uxpA[k] - uxmA[k]) * 127.5f;   // scaled inputs
        const float dvdx = (vxpA[k] - vxmA[k]) * 127.5f;
        const float dpdx = (pxpA[k] - pxmA[k]) * sdx;      // raw p
        const float dudy = (ur[k] - ul[k]) * 127.5f;
        const float dvdy = (vr[k] - vl[k]) * 127.5f;
        const float dpdy = (pr[k] - pl[k]) * sdx;
        const float lapu = (uxpA[k] + uxmA[k] + ur[k] + ul[k]) * 0.65025f
                         - 2.601f * ucA[k];
        const float lapv = (vxpA[k] + vxmA[k] + vr[k] + vl[k]) * 0.65025f
                         - 2.601f * vcA[k];
        r0[k] = fabsf(dudx + dvdy);
        r1[k] = fabsf((unA[k] - umA[k]) * 32.0f + ucA[k] * dudx + vcA[k] * dudy
                      + dpdx - lapu);
        r2[k] = fabsf((vnA[k] - vmA[k]) * 32.0f + ucA[k] * dvdx + vcA[k] * dvdy
                      + dpdy - lapv);
    }
}

__global__ __launch_bounds__(256)
void ns_loss_kernel(const float* __restrict__ X, const float* __restrict__ Y,
                    const float* __restrict__ stdp, double* __restrict__ acc)
{
    __shared__ float lds[2][3][4][256];     // 24 KiB
    __shared__ float smr[3][4];

    const float s   = *stdp;
    const float sdx = s * 127.5f;

    // XCD swizzle: nwg = 1024 = 8*128; each XCD owns one (z,jh) group
    // of 128 contiguous i-bands.
    const int orig = blockIdx.x;
    const int wg   = (orig & 7) * 128 + (orig >> 3);
    const int z    = wg >> 8;              // b-chunk 0..3
    const int rem  = wg & 255;
    const int jh   = rem >> 7;             // j-half 0..1
    const int band = rem & 127;            // i-band 0..127

    const int tid = threadIdx.x;
    const int io  = tid >> 6;              // row in band 0..3 (wave-uniform)
    const int jt  = tid & 63;              // f4-col in half-row
    const int jl  = jt << 2;               // LDS float col 0..252
    const int j0g = (jh << 8) + jl;        // global float col
    const int irow = 1 + band * 4 + io;
    const int i    = min(irow, 511);
    const bool vrow = (irow <= 510);
    const int bs = 1 + 15 * z + (z == 3 ? 1 : 0);   // 1,16,31,47
    const int nsteps = (z < 2) ? 15 : 16;

    int c = bs * BSTR + i * Wd + j0g;
    const int cup  = (i < 511) ? Wd : 0;
    const int eoff = (io == 0) ? -Wd : cup;          // band-edge row offset
    const bool isedge = (io == 0) || (io == 3);
    const int offL = (j0g == 0) ? 0 : -1;            // clamped, masked at k=0
    const int offR = (j0g == 508) ? 3 : 4;           // clamped, masked at k=3

    // ---- prologue: plane bs ----
    float4 xmu = scale4(ld4(X + c - BSTR), s);
    float4 xcu = scale4(ld4(X + c), s);
    float4 xmv = scale4(ld4(X + c - BSTR + CSTR), s);
    float4 xcv = scale4(ld4(X + c + CSTR), s);
    float4 ymu = scale4(ld4(Y + c - BSTR), s);
    float4 ycu = scale4(ld4(Y + c), s);
    float4 ymv = scale4(ld4(Y + c - BSTR + CSTR), s);
    float4 ycv = scale4(ld4(Y + c + CSTR), s);
    float4 xnu = ld4(X + c + BSTR);                  // raw u(b+1)
    float4 xnv = ld4(X + c + BSTR + CSTR);
    float4 xcp = ld4(X + c + 2 * CSTR);              // raw p center
    float4 ynu = ld4(Y + c + BSTR);
    float4 ynv = ld4(Y + c + BSTR + CSTR);
    float4 ycp = ld4(Y + c + 2 * CSTR);
    float4 xeu = make_float4(0,0,0,0), xev = xeu, xep = xeu;
    float4 yeu = xeu, yev = xeu, yep = xeu;
    if (isedge) {
        xeu = scale4(ld4(X + c + eoff), s);
        xev = scale4(ld4(X + c + CSTR + eoff), s);
        xep = ld4(X + c + 2 * CSTR + eoff);
        yeu = scale4(ld4(Y + c + eoff), s);
        yev = scale4(ld4(Y + c + CSTR + eoff), s);
        yep = ld4(Y + c + 2 * CSTR + eoff);
    }
    float xul = 0, xvl = 0, xpl = 0, yul = 0, yvl = 0, ypl = 0;
    float xur = 0, xvr = 0, xpr = 0, yur = 0, yvr = 0, ypr = 0;
    if (jt == 0) {
        xul = X[c + offL] * s; xvl = X[c + CSTR + offL] * s;
        xpl = X[c + 2 * CSTR + offL];
        yul = Y[c + offL] * s; yvl = Y[c + CSTR + offL] * s;
        ypl = Y[c + 2 * CSTR + offL];
    }
    if (jt == 63) {
        xur = X[c + offR] * s; xvr = X[c + CSTR + offR] * s;
        xpr = X[c + 2 * CSTR + offR];
        yur = Y[c + offR] * s; yvr = Y[c + CSTR + offR] * s;
        ypr = Y[c + 2 * CSTR + offR];
    }

    float s0 = 0.0f, s1 = 0.0f, s2 = 0.0f;

    for (int it = 0; it < nsteps; ++it) {
        const int cn = c + ((it + 1 < nsteps) ? BSTR : 0);

        // ---- 1. stage current plane from registers ----
        *(float4*)&lds[0][0][io][jl] = xcu;
        *(float4*)&lds[0][1][io][jl] = xcv;
        *(float4*)&lds[0][2][io][jl] = xcp;
        *(float4*)&lds[1][0][io][jl] = ycu;
        *(float4*)&lds[1][1][io][jl] = ycv;
        *(float4*)&lds[1][2][io][jl] = ycp;
        asm volatile("s_waitcnt lgkmcnt(0)" ::: "memory");
        __builtin_amdgcn_s_barrier();    // global prefetches stay in flight

        // ---- 2. snapshot b+1 centers, issue next-plane prefetch ----
        const float4 xnus = scale4(xnu, s), xnvs = scale4(xnv, s);
        const float4 ynus = scale4(ynu, s), ynvs = scale4(ynv, s);
        xnu = ld4(X + cn + BSTR);
        xnv = ld4(X + cn + BSTR + CSTR);
        ynu = ld4(Y + cn + BSTR);
        ynv = ld4(Y + cn + BSTR + CSTR);
        float4 xcp2 = ld4(X + cn + 2 * CSTR);
        float4 ycp2 = ld4(Y + cn + 2 * CSTR);
        float4 xeu2 = xeu, xev2 = xev, xep2 = xep;
        float4 yeu2 = yeu, yev2 = yev, yep2 = yep;
        if (isedge) {
            xeu2 = scale4(ld4(X + cn + eoff), s);
            xev2 = scale4(ld4(X + cn + CSTR + eoff), s);
            xep2 = ld4(X + cn + 2 * CSTR + eoff);
            yeu2 = scale4(ld4(Y + cn + eoff), s);
            yev2 = scale4(ld4(Y + cn + CSTR + eoff), s);
            yep2 = ld4(Y + cn + 2 * CSTR + eoff);
        }
        float xul2 = xul, xvl2 = xvl, xpl2 = xpl;
        float yul2 = yul, yvl2 = yvl, ypl2 = ypl;
        float xur2 = xur, xvr2 = xvr, xpr2 = xpr;
        float yur2 = yur, yvr2 = yvr, ypr2 = ypr;
        if (jt == 0) {
            xul2 = X[cn + offL] * s; xvl2 = X[cn + CSTR + offL] * s;
            xpl2 = X[cn + 2 * CSTR + offL];
            yul2 = Y[cn + offL] * s; yvl2 = Y[cn + CSTR + offL] * s;
            ypl2 = Y[cn + 2 * CSTR + offL];
        }
        if (jt == 63) {
            xur2 = X[cn + offR] * s; xvr2 = X[cn + CSTR + offR] * s;
            xpr2 = X[cn + 2 * CSTR + offR];
            yur2 = Y[cn + offR] * s; yvr2 = Y[cn + CSTR + offR] * s;
            ypr2 = Y[cn + 2 * CSTR + offR];
        }

        // ---- 3. compute from LDS + regs ----
        float r0x[4], r1x[4], r2x[4], r0y[4], r1y[4], r2y[4];
        plane_resid(lds[0], io, jt, jl, xeu, xev, xep,
                    xmu, xcu, xnus, xmv, xcv, xnvs, xcp,
                    xul, xvl, xpl, xur, xvr, xpr, sdx, r0x, r1x, r2x);
        plane_resid(lds[1], io, jt, jl, yeu, yev, yep,
                    ymu, ycu, ynus, ymv, ycv, ynvs, ycp,
                    yul, yvl, ypl, yur, yvr, ypr, sdx, r0y, r1y, r2y);

        // ---- 4. accumulate (masked) ----
        #pragma unroll
        for (int k = 0; k < 4; ++k) {
            float e0 = r0y[k] - r0x[k];
            float e1 = r1y[k] - r1x[k];
            float e2 = r2y[k] - r2x[k];
            const bool dead = (!vrow) || (k == 0 && j0g == 0)
                                      || (k == 3 && j0g == 508);
            if (dead) { e0 = 0.0f; e1 = 0.0f; e2 = 0.0f; }
            s0 += e0 * e0; s1 += e1 * e1; s2 += e2 * e2;
        }

        // ---- 5. rotate carries; barrier before next overwrite ----
        xmu = xcu; xcu = xnus; xmv = xcv; xcv = xnvs;
        ymu = ycu; ycu = ynus; ymv = ycv; ycv = ynvs;
        xcp = xcp2; ycp = ycp2;
        xeu = xeu2; xev = xev2; xep = xep2;
        yeu = yeu2; yev = yev2; yep = yep2;
        xul = xul2; xvl = xvl2; xpl = xpl2;
        yul = yul2; yvl = yvl2; ypl = ypl2;
        xur = xur2; xvr = xvr2; xpr = xpr2;
        yur = yur2; yvr = yvr2; ypr = ypr2;
        asm volatile("s_waitcnt lgkmcnt(0)" ::: "memory");
        __builtin_amdgcn_s_barrier();
        c = cn;
    }

    // ---- reduction: f32 wave shuffle -> LDS -> f64 atomic ----
    for (int o = 32; o > 0; o >>= 1) {
        s0 += __shfl_down(s0, o);
        s1 += __shfl_down(s1, o);
        s2 += __shfl_down(s2, o);
    }
    const int wid = tid >> 6;
    if (jt == 0) { smr[0][wid] = s0; smr[1][wid] = s1; smr[2][wid] = s2; }
    __syncthreads();
    if (tid == 0) {
        atomicAdd(&acc[0], (double)smr[0][0] + (double)smr[0][1]
                         + (double)smr[0][2] + (double)smr[0][3]);
        atomicAdd(&acc[1], (double)smr[1][0] + (double)smr[1][1]
                         + (double)smr[1][2] + (double)smr[1][3]);
        atomicAdd(&acc[2], (double)smr[2][0] + (double)smr[2][1]
                         + (double)smr[2][2] + (double)smr[2][3]);
    }
}

__global__ void ns_finalize_kernel(const double* __restrict__ acc,
                                   float* __restrict__ out)
{
    if (threadIdx.x == 0) {
        const double N = 62.0 * 510.0 * 510.0;
        out[0] = (float)(1.0e-3 * (acc[0] + acc[1] + acc[2]) / N);
    }
}

extern "C" void kernel_launch(void* const* d_in, const int* in_sizes, int n_in,
                              void* d_out, int out_size, void* d_ws, size_t ws_size,
                              hipStream_t stream) {
    const float* X    = (const float*)d_in[0];
    const float* Y    = (const float*)d_in[1];
    const float* stdp = (const float*)d_in[2];
    float* out  = (float*)d_out;
    double* acc = (double*)d_ws;

    hipMemsetAsync(acc, 0, 3 * sizeof(double), stream);

    dim3 block(256);
    dim3 grid(1024);  // 4 b-chunks x 2 j-halves x 128 bands; 4-5 blk/CU
    ns_loss_kernel<<<grid, block, 0, stream>>>(X, Y, stdp, acc);
    ns_finalize_kernel<<<1, 64, 0, stream>>>(acc, out);
}